// Round 3
// baseline (691.909 us; speedup 1.0000x reference)
//
#include <hip/hip_runtime.h>
#include <math.h>

typedef unsigned short u16;
typedef unsigned int u32;
typedef __bf16 b16x8 __attribute__((ext_vector_type(8)));
typedef float f32x4 __attribute__((ext_vector_type(4)));

#define BS 16
#define DSC 8
#define QL 512
#define DM 256
#define NH 16
#define DKH 16
#define DC 128
#define DFF 1024
#define S_TOT 4096
#define R_TOT 65536

static __device__ __forceinline__ u16 f2bf(float f) {
  u32 u = __float_as_uint(f);
  u += 0x7fffu + ((u >> 16) & 1u);   // RNE
  return (u16)(u >> 16);
}
static __device__ __forceinline__ float bflo(u32 u) { return __uint_as_float(u << 16); }
static __device__ __forceinline__ float bfhi(u32 u) { return __uint_as_float(u & 0xffff0000u); }

static __device__ __forceinline__ uint4 pack8(float4 a, float4 b) {
  uint4 o;
  o.x = (u32)f2bf(a.x) | ((u32)f2bf(a.y) << 16);
  o.y = (u32)f2bf(a.z) | ((u32)f2bf(a.w) << 16);
  o.z = (u32)f2bf(b.x) | ((u32)f2bf(b.y) << 16);
  o.w = (u32)f2bf(b.z) | ((u32)f2bf(b.w) << 16);
  return o;
}

// ---------------- f32 -> bf16 convert (weights only; vectorized) ---------------
__global__ void cvt_kernel(const float* __restrict__ in, u16* __restrict__ outp, int n4) {
  for (int i = blockIdx.x * blockDim.x + threadIdx.x; i < n4; i += gridDim.x * blockDim.x) {
    float4 v = *(const float4*)(in + (size_t)i * 4);
    uint2 o;
    o.x = (u32)f2bf(v.x) | ((u32)f2bf(v.y) << 16);
    o.y = (u32)f2bf(v.z) | ((u32)f2bf(v.w) << 16);
    *(uint2*)(outp + (size_t)i * 4) = o;
  }
}

// ---------------- out_w transpose (256x256 f32) ----------------
__global__ void transp_kernel(const float* __restrict__ w, float* __restrict__ wt) {
  int i = blockIdx.x * 256 + threadIdx.x;  // 65536
  int k = i >> 8, n = i & 255;
  wt[i] = w[n * 256 + k];
}

// ---------------- bf16 MFMA GEMM: C[M,N] = A[M,K] * B[N,K]^T (+epilogue) -------
// 128x128 tile, BK=32, 256 threads (4 waves, each 64x64 = 4x4 frags of 16x16x32).
// LDS rows padded to 40 shorts (80B): frag ds_read_b128 ~2-way conflicts (free).
// AF32: A is f32 in global, converted to bf16 in-register during staging.
// EPI: 0 = +bias -> bf16 out ; 1 = gelu(x+bias) -> bf16 out ; 2 = +bias+resid -> f32 out
template <int EPI, int AF32>
__global__ __launch_bounds__(256) void gemm_bf16(
    const void* __restrict__ Av, const u16* __restrict__ B,
    const float* __restrict__ bias, const float* __restrict__ resid,
    void* __restrict__ out, int K, int ldo) {
  __shared__ __align__(16) u16 As[128 * 40];
  __shared__ __align__(16) u16 Bs[128 * 40];
  const int m0 = blockIdx.x * 128, n0 = blockIdx.y * 128;
  const int tid = threadIdx.x;
  const int w = tid >> 6, lane = tid & 63;
  const int wm = (w >> 1) * 64, wn = (w & 1) * 64;
  const int fr = lane & 15, fq = lane >> 4;

  f32x4 acc[4][4];
#pragma unroll
  for (int i = 0; i < 4; i++)
#pragma unroll
    for (int j = 0; j < 4; j++) acc[i][j] = (f32x4){0.f, 0.f, 0.f, 0.f};

  const u16* Bg = B + (size_t)n0 * K;
  const int r0 = tid >> 2, o0 = (tid & 3) * 8;          // rows 0..63, k-chunk o0
  const int r1 = r0 + 64;                               // rows 64..127

  for (int k0 = 0; k0 < K; k0 += 32) {
    uint4 a0, a1;
    if (AF32) {
      const float* Agf = (const float*)Av + (size_t)m0 * K;
      float4 l0 = *(const float4*)(Agf + (size_t)r0 * K + k0 + o0);
      float4 h0 = *(const float4*)(Agf + (size_t)r0 * K + k0 + o0 + 4);
      float4 l1 = *(const float4*)(Agf + (size_t)r1 * K + k0 + o0);
      float4 h1 = *(const float4*)(Agf + (size_t)r1 * K + k0 + o0 + 4);
      a0 = pack8(l0, h0);
      a1 = pack8(l1, h1);
    } else {
      const u16* Ag = (const u16*)Av + (size_t)m0 * K;
      a0 = *(const uint4*)(Ag + (size_t)r0 * K + k0 + o0);
      a1 = *(const uint4*)(Ag + (size_t)r1 * K + k0 + o0);
    }
    uint4 b0 = *(const uint4*)(Bg + (size_t)r0 * K + k0 + o0);
    uint4 b1 = *(const uint4*)(Bg + (size_t)r1 * K + k0 + o0);
    __syncthreads();
    *(uint4*)&As[r0 * 40 + o0] = a0;
    *(uint4*)&As[r1 * 40 + o0] = a1;
    *(uint4*)&Bs[r0 * 40 + o0] = b0;
    *(uint4*)&Bs[r1 * 40 + o0] = b1;
    __syncthreads();

    uint4 af[4], bf[4];
#pragma unroll
    for (int i = 0; i < 4; i++) {
      af[i] = *(const uint4*)&As[(wm + i * 16 + fr) * 40 + fq * 8];
      bf[i] = *(const uint4*)&Bs[(wn + i * 16 + fr) * 40 + fq * 8];
    }
#pragma unroll
    for (int mi = 0; mi < 4; mi++)
#pragma unroll
      for (int ni = 0; ni < 4; ni++)
        acc[mi][ni] = __builtin_amdgcn_mfma_f32_16x16x32_bf16(
            __builtin_bit_cast(b16x8, af[mi]), __builtin_bit_cast(b16x8, bf[ni]),
            acc[mi][ni], 0, 0, 0);
  }

  // epilogue: D row = fq*4 + reg, col = fr (measured C/D layout for 16x16x32)
#pragma unroll
  for (int ni = 0; ni < 4; ni++) {
    const int gc = n0 + wn + ni * 16 + fr;
    const float bv = bias[gc];
#pragma unroll
    for (int mi = 0; mi < 4; mi++) {
#pragma unroll
      for (int r = 0; r < 4; r++) {
        const int gr = m0 + wm + mi * 16 + fq * 4 + r;
        float v = acc[mi][ni][r] + bv;
        if (EPI == 1) v = 0.5f * v * (1.f + erff(v * 0.70710678118f));
        if (EPI == 2) {
          v += resid[(size_t)gr * ldo + gc];
          ((float*)out)[(size_t)gr * ldo + gc] = v;
        } else {
          ((u16*)out)[(size_t)gr * ldo + gc] = f2bf(v);
        }
      }
    }
  }
}

// ---------------- compressed attention: block per (b,h), 16 waves over S -------
// scores[c,s] = 0.25 * router[h,c,:].k[b,s,h,:]; softmax over s (max-free: |score|<~0.3);
// ctx[c,:] = sum_s p * k. Lane owns c = lane and lane+64; wave owns 256 s-rows.
__global__ __launch_bounds__(1024) void attn_kernel(const u16* __restrict__ kbf,
                                                    const float* __restrict__ router,
                                                    float* __restrict__ ctxb) {
  const int bh = blockIdx.x, b = bh >> 4, h = bh & 15;
  const int tid = threadIdx.x, w = tid >> 6, lane = tid & 63;
  __shared__ float part[16 * 32 * 17];  // 34.8 KB partials, combined in 4 c-chunks

  float rc0[16], rc1[16];
  const float* rbase = router + (size_t)h * DC * DKH;
#pragma unroll
  for (int d = 0; d < 16; d++) {
    rc0[d] = rbase[(size_t)lane * 16 + d] * 0.25f;        // fold scale = dk^-0.5
    rc1[d] = rbase[(size_t)(lane + 64) * 16 + d] * 0.25f;
  }

  const u32* kg = (const u32*)kbf + (size_t)b * S_TOT * 128 + h * 8;  // row stride 128 u32
  const int s0 = w * 256;
  float l0 = 0.f, l1 = 0.f;
  float cx0[16], cx1[16];
#pragma unroll
  for (int d = 0; d < 16; d++) { cx0[d] = 0.f; cx1[d] = 0.f; }

  for (int it = 0; it < 128; it++) {
    const u32* p0 = kg + (size_t)(s0 + 2 * it) * 128;
    const u32* p1 = p0 + 128;
    u32 ra[8], rb[8];
#pragma unroll
    for (int j = 0; j < 8; j++) ra[j] = p0[j];   // wave-uniform broadcast loads
#pragma unroll
    for (int j = 0; j < 8; j++) rb[j] = p1[j];
#pragma unroll
    for (int half = 0; half < 2; half++) {
      float kv[16];
#pragma unroll
      for (int j = 0; j < 8; j++) {
        u32 uu = half ? rb[j] : ra[j];
        kv[2 * j] = bflo(uu);
        kv[2 * j + 1] = bfhi(uu);
      }
      float sA = 0.f, sB = 0.f;
#pragma unroll
      for (int d = 0; d < 16; d++) { sA += rc0[d] * kv[d]; sB += rc1[d] * kv[d]; }
      float pA = __expf(sA), pB = __expf(sB);
      l0 += pA; l1 += pB;
#pragma unroll
      for (int d = 0; d < 16; d++) { cx0[d] += pA * kv[d]; cx1[d] += pB * kv[d]; }
    }
  }

  // combine 16 waves' partials, 32 c's at a time
  for (int ch = 0; ch < 4; ch++) {
    __syncthreads();
    const int clo = ch * 32;
    if (lane >= clo && lane < clo + 32) {
      float* p = &part[(w * 32 + (lane - clo)) * 17];
      p[0] = l0;
#pragma unroll
      for (int d = 0; d < 16; d++) p[1 + d] = cx0[d];
    }
    const int c1 = lane + 64;
    if (c1 >= clo && c1 < clo + 32) {
      float* p = &part[(w * 32 + (c1 - clo)) * 17];
      p[0] = l1;
#pragma unroll
      for (int d = 0; d < 16; d++) p[1 + d] = cx1[d];
    }
    __syncthreads();
    if (tid < 512) {
      const int c = tid >> 4, d = tid & 15;
      float L = 0.f, v = 0.f;
#pragma unroll
      for (int ww = 0; ww < 16; ww++) {
        const float* p = &part[(ww * 32 + c) * 17];
        L += p[0];
        v += p[1 + d];
      }
      ctxb[((size_t)b * DC + clo + c) * (NH * DKH) + h * 16 + d] = v / L;
    }
  }
}

// ---------------- ar[b,c,:] = ctx[b,c,:] @ out_w^T + out_b + pos_embd[c,:] -----
__global__ __launch_bounds__(256) void ar_kernel(const float* __restrict__ ctxb,
                                                 const float* __restrict__ owT,
                                                 const float* __restrict__ ob,
                                                 const float* __restrict__ pos,
                                                 float* __restrict__ ar) {
  const int b = blockIdx.x, g = blockIdx.y, n = threadIdx.x;
  __shared__ float cl[8][256];
#pragma unroll
  for (int j = 0; j < 8; j++)
    cl[j][n] = ctxb[((size_t)b * DC + g * 8 + j) * 256 + n];
  __syncthreads();
  float acc[8];
#pragma unroll
  for (int j = 0; j < 8; j++) acc[j] = ob[n] + pos[(size_t)(g * 8 + j) * 256 + n];
  for (int k = 0; k < 256; k++) {
    float wv = owT[(size_t)k * 256 + n];
#pragma unroll
    for (int j = 0; j < 8; j++) acc[j] += cl[j][k] * wv;
  }
#pragma unroll
  for (int j = 0; j < 8; j++) ar[((size_t)b * DC + g * 8 + j) * 256 + n] = acc[j];
}

// ---------------- t[b,q,:] = sum_c m_expand[q,c] * ar[b,c,:] -------------------
__global__ __launch_bounds__(256) void texp_kernel(const float* __restrict__ me,
                                                   const float* __restrict__ ar,
                                                   float* __restrict__ tb) {
  const int b = blockIdx.x, qg = blockIdx.y, d = threadIdx.x;
  __shared__ float ml[16][128];
  const int q0 = qg * 16;
  for (int i = threadIdx.x; i < 16 * 128; i += 256) {
    int qq = i >> 7, c = i & 127;
    ml[qq][c] = me[(size_t)(q0 + qq) * 128 + c];
  }
  __syncthreads();
  float acc[16];
#pragma unroll
  for (int qq = 0; qq < 16; qq++) acc[qq] = 0.f;
  for (int c = 0; c < 128; c++) {
    float v = ar[((size_t)b * DC + c) * 256 + d];
#pragma unroll
    for (int qq = 0; qq < 16; qq++) acc[qq] += ml[qq][c] * v;
  }
#pragma unroll
  for (int qq = 0; qq < 16; qq++)
    tb[((size_t)(b * QL + q0 + qq)) * 256 + d] = acc[qq];
}

// ---------------- LN1: y = LN(src + scale_tf[x]*t) ; write f32 y to d_out ------
__global__ __launch_bounds__(256) void ln1_kernel(
    const float* __restrict__ src, const float* __restrict__ tbuf,
    const float* __restrict__ stf, const float* __restrict__ g,
    const float* __restrict__ bb, float* __restrict__ yout) {
  const int w = threadIdx.x >> 6, lane = threadIdx.x & 63;
  const int r = blockIdx.x * 4 + w;
  const int b = r >> 12, x = (r >> 9) & 7, q = r & 511;
  const size_t base = (size_t)r * DM + lane * 4;
  float4 s4 = *(const float4*)(src + base);
  float4 t4 = *(const float4*)(tbuf + ((size_t)(b * QL + q) * DM + lane * 4));
  const float sc = stf[x];
  float v0 = s4.x + sc * t4.x, v1 = s4.y + sc * t4.y;
  float v2 = s4.z + sc * t4.z, v3 = s4.w + sc * t4.w;
  float sum = v0 + v1 + v2 + v3;
  float sq = v0 * v0 + v1 * v1 + v2 * v2 + v3 * v3;
#pragma unroll
  for (int off = 32; off; off >>= 1) {
    sum += __shfl_xor(sum, off);
    sq += __shfl_xor(sq, off);
  }
  const float mean = sum * (1.f / DM);
  const float var = sq * (1.f / DM) - mean * mean;
  const float rs = rsqrtf(var + 1e-5f);
  float4 gv = *(const float4*)(g + lane * 4);
  float4 bv = *(const float4*)(bb + lane * 4);
  float4 o;
  o.x = (v0 - mean) * rs * gv.x + bv.x;
  o.y = (v1 - mean) * rs * gv.y + bv.y;
  o.z = (v2 - mean) * rs * gv.z + bv.z;
  o.w = (v3 - mean) * rs * gv.w + bv.w;
  *(float4*)(yout + base) = o;
}

// ---------------- LN2: in-place on d_out --------------------------------------
__global__ __launch_bounds__(256) void ln2_kernel(float* __restrict__ io,
                                                  const float* __restrict__ g,
                                                  const float* __restrict__ bb) {
  const int w = threadIdx.x >> 6, lane = threadIdx.x & 63;
  const int r = blockIdx.x * 4 + w;
  const size_t base = (size_t)r * DM + lane * 4;
  float4 v4 = *(const float4*)(io + base);
  float sum = v4.x + v4.y + v4.z + v4.w;
  float sq = v4.x * v4.x + v4.y * v4.y + v4.z * v4.z + v4.w * v4.w;
#pragma unroll
  for (int off = 32; off; off >>= 1) {
    sum += __shfl_xor(sum, off);
    sq += __shfl_xor(sq, off);
  }
  const float mean = sum * (1.f / DM);
  const float var = sq * (1.f / DM) - mean * mean;
  const float rs = rsqrtf(var + 1e-5f);
  float4 gv = *(const float4*)(g + lane * 4);
  float4 bv = *(const float4*)(bb + lane * 4);
  float4 o;
  o.x = (v4.x - mean) * rs * gv.x + bv.x;
  o.y = (v4.y - mean) * rs * gv.y + bv.y;
  o.z = (v4.z - mean) * rs * gv.z + bv.z;
  o.w = (v4.w - mean) * rs * gv.w + bv.w;
  *(float4*)(io + base) = o;
}

extern "C" void kernel_launch(void* const* d_in, const int* in_sizes, int n_in,
                              void* d_out, int out_size, void* d_ws, size_t ws_size,
                              hipStream_t stream) {
  const float* src = (const float*)d_in[0];
  const float* router = (const float*)d_in[1];
  const float* wk_w = (const float*)d_in[2];
  const float* wk_b = (const float*)d_in[3];
  const float* out_w = (const float*)d_in[4];
  const float* out_b = (const float*)d_in[5];
  const float* m_exp = (const float*)d_in[6];
  const float* pos = (const float*)d_in[7];
  const float* stf = (const float*)d_in[8];
  const float* ln1g = (const float*)d_in[9];
  const float* ln1b = (const float*)d_in[10];
  const float* f1w = (const float*)d_in[11];
  const float* f1b = (const float*)d_in[12];
  const float* f2w = (const float*)d_in[13];
  const float* f2b = (const float*)d_in[14];
  const float* ln2g = (const float*)d_in[15];
  const float* ln2b = (const float*)d_in[16];
  float* out = (float*)d_out;

  unsigned char* ws = (unsigned char*)d_ws;
  u16* k_bf = (u16*)(ws + 0);               // 33,554,432 B
  u16* h_bf = (u16*)(ws + 33554432);        // 134,217,728 B
  u16* wkw_bf = (u16*)(ws + 167772160);     // 131,072 B
  u16* f1w_bf = (u16*)(ws + 167903232);     // 524,288 B
  u16* f2w_bf = (u16*)(ws + 168427520);     // 524,288 B
  float* owT = (float*)(ws + 168951808);    // 262,144 B
  float* ctxb = (float*)(ws + 169213952);   // 2,097,152 B
  float* arb = (float*)(ws + 171311104);    // 2,097,152 B
  float* tb = (float*)(ws + 173408256);     // 8,388,608 B  (total 181,796,864 B)

  cvt_kernel<<<64, 256, 0, stream>>>(wk_w, wkw_bf, 256 * 256 / 4);
  cvt_kernel<<<256, 256, 0, stream>>>(f1w, f1w_bf, DFF * DM / 4);
  cvt_kernel<<<256, 256, 0, stream>>>(f2w, f2w_bf, DM * DFF / 4);
  transp_kernel<<<256, 256, 0, stream>>>(out_w, owT);

  // K-projection: k = src @ Wk_w^T + Wk_b  (f32 A staged->bf16; bf16 out [b*S][h*16+d])
  gemm_bf16<0, 1><<<dim3(512, 2), 256, 0, stream>>>(src, wkw_bf, wk_b, nullptr,
                                                    k_bf, DM, DM);
  attn_kernel<<<256, 1024, 0, stream>>>(k_bf, router, ctxb);
  ar_kernel<<<dim3(16, 16), 256, 0, stream>>>(ctxb, owT, out_b, pos, arb);
  texp_kernel<<<dim3(16, 32), 256, 0, stream>>>(m_exp, arb, tb);
  ln1_kernel<<<16384, 256, 0, stream>>>(src, tb, stf, ln1g, ln1b, out);

  // FFN1: h = gelu(y @ ff1_w^T + b1)  (f32 A = d_out, bf16 h in ws)
  gemm_bf16<1, 1><<<dim3(512, 8), 256, 0, stream>>>(out, f1w_bf, f1b, nullptr,
                                                    h_bf, DM, DFF);
  // FFN2: pre-LN2 = y + h @ ff2_w^T + b2  (f32, in-place on d_out)
  gemm_bf16<2, 0><<<dim3(512, 2), 256, 0, stream>>>(h_bf, f2w_bf, f2b, out,
                                                    out, DFF, DM);
  ln2_kernel<<<16384, 256, 0, stream>>>(out, ln2g, ln2b);
}

// Round 5
// 492.309 us; speedup vs baseline: 1.4054x; 1.4054x over previous
//
#include <hip/hip_runtime.h>
#include <math.h>

typedef unsigned short u16;
typedef unsigned int u32;
typedef __bf16 b16x8 __attribute__((ext_vector_type(8)));
typedef float f32x4 __attribute__((ext_vector_type(4)));

#define BS 16
#define DSC 8
#define QL 512
#define DM 256
#define NH 16
#define DKH 16
#define DC 128
#define DFF 1024
#define S_TOT 4096
#define R_TOT 65536
#define ATT_SCALE 0.36067376022224085f  // 0.25 * log2(e)

static __device__ __forceinline__ u16 f2bf(float f) {
  u32 u = __float_as_uint(f);
  u += 0x7fffu + ((u >> 16) & 1u);   // RNE
  return (u16)(u >> 16);
}

static __device__ __forceinline__ uint4 pack8(float4 a, float4 b) {
  uint4 o;
  o.x = (u32)f2bf(a.x) | ((u32)f2bf(a.y) << 16);
  o.y = (u32)f2bf(a.z) | ((u32)f2bf(a.w) << 16);
  o.z = (u32)f2bf(b.x) | ((u32)f2bf(b.y) << 16);
  o.w = (u32)f2bf(b.z) | ((u32)f2bf(b.w) << 16);
  return o;
}

// ---------------- f32 -> bf16 convert (weights only; vectorized) ---------------
__global__ void cvt_kernel(const float* __restrict__ in, u16* __restrict__ outp, int n4) {
  for (int i = blockIdx.x * blockDim.x + threadIdx.x; i < n4; i += gridDim.x * blockDim.x) {
    float4 v = *(const float4*)(in + (size_t)i * 4);
    uint2 o;
    o.x = (u32)f2bf(v.x) | ((u32)f2bf(v.y) << 16);
    o.y = (u32)f2bf(v.z) | ((u32)f2bf(v.w) << 16);
    *(uint2*)(outp + (size_t)i * 4) = o;
  }
}

// ---------------- out_w transpose (256x256 f32) ----------------
__global__ void transp_kernel(const float* __restrict__ w, float* __restrict__ wt) {
  int i = blockIdx.x * 256 + threadIdx.x;  // 65536
  int k = i >> 8, n = i & 255;
  wt[i] = w[n * 256 + k];
}

// ---------------- bf16 MFMA GEMM: C[M,N] = A[M,K] * B[N,K]^T (+epilogue) -------
// 128x128 tile, BK=32, 256 threads (4 waves, each 64x64 = 4x4 frags of 16x16x32).
// LDS rows padded to 40 shorts (80B): frag ds_read_b128 ~2-way conflicts (free).
// 1-D grid, XCD-chunked swizzle: XCD x owns m-tiles [x*64, x*64+64), cycles the
// NTY column-tiles fastest so each A-tile stays L2-resident for all its columns.
// AF32: A is f32 in global, converted to bf16 in-register during staging.
// EPI: 0 = +bias -> bf16 out ; 1 = gelu(x+bias) -> bf16 out ; 2 = +bias+resid -> f32 out
template <int EPI, int AF32, int NTY>
__global__ __launch_bounds__(256) void gemm_bf16(
    const void* __restrict__ Av, const u16* __restrict__ B,
    const float* __restrict__ bias, const float* __restrict__ resid,
    void* __restrict__ out, int K, int ldo) {
  __shared__ __align__(16) u16 As[128 * 40];
  __shared__ __align__(16) u16 Bs[128 * 40];
  const int g = blockIdx.x;
  const int xcd = g & 7, tt = g >> 3;
  const int m0 = (xcd * 64 + tt / NTY) * 128;
  const int n0 = (tt % NTY) * 128;
  const int tid = threadIdx.x;
  const int w = tid >> 6, lane = tid & 63;
  const int wm = (w >> 1) * 64, wn = (w & 1) * 64;
  const int fr = lane & 15, fq = lane >> 4;

  f32x4 acc[4][4];
#pragma unroll
  for (int i = 0; i < 4; i++)
#pragma unroll
    for (int j = 0; j < 4; j++) acc[i][j] = (f32x4){0.f, 0.f, 0.f, 0.f};

  const u16* Bg = B + (size_t)n0 * K;
  const int r0 = tid >> 2, o0 = (tid & 3) * 8;          // rows 0..63, k-chunk o0
  const int r1 = r0 + 64;                               // rows 64..127

  for (int k0 = 0; k0 < K; k0 += 32) {
    uint4 a0, a1;
    if (AF32) {
      const float* Agf = (const float*)Av + (size_t)m0 * K;
      float4 l0 = *(const float4*)(Agf + (size_t)r0 * K + k0 + o0);
      float4 h0 = *(const float4*)(Agf + (size_t)r0 * K + k0 + o0 + 4);
      float4 l1 = *(const float4*)(Agf + (size_t)r1 * K + k0 + o0);
      float4 h1 = *(const float4*)(Agf + (size_t)r1 * K + k0 + o0 + 4);
      a0 = pack8(l0, h0);
      a1 = pack8(l1, h1);
    } else {
      const u16* Ag = (const u16*)Av + (size_t)m0 * K;
      a0 = *(const uint4*)(Ag + (size_t)r0 * K + k0 + o0);
      a1 = *(const uint4*)(Ag + (size_t)r1 * K + k0 + o0);
    }
    uint4 b0 = *(const uint4*)(Bg + (size_t)r0 * K + k0 + o0);
    uint4 b1 = *(const uint4*)(Bg + (size_t)r1 * K + k0 + o0);
    __syncthreads();
    *(uint4*)&As[r0 * 40 + o0] = a0;
    *(uint4*)&As[r1 * 40 + o0] = a1;
    *(uint4*)&Bs[r0 * 40 + o0] = b0;
    *(uint4*)&Bs[r1 * 40 + o0] = b1;
    __syncthreads();

    uint4 af[4], bf[4];
#pragma unroll
    for (int i = 0; i < 4; i++) {
      af[i] = *(const uint4*)&As[(wm + i * 16 + fr) * 40 + fq * 8];
      bf[i] = *(const uint4*)&Bs[(wn + i * 16 + fr) * 40 + fq * 8];
    }
#pragma unroll
    for (int mi = 0; mi < 4; mi++)
#pragma unroll
      for (int ni = 0; ni < 4; ni++)
        acc[mi][ni] = __builtin_amdgcn_mfma_f32_16x16x32_bf16(
            __builtin_bit_cast(b16x8, af[mi]), __builtin_bit_cast(b16x8, bf[ni]),
            acc[mi][ni], 0, 0, 0);
  }

  // epilogue: D row = fq*4 + reg, col = fr (measured C/D layout for 16x16x32)
#pragma unroll
  for (int ni = 0; ni < 4; ni++) {
    const int gc = n0 + wn + ni * 16 + fr;
    const float bv = bias[gc];
#pragma unroll
    for (int mi = 0; mi < 4; mi++) {
#pragma unroll
      for (int r = 0; r < 4; r++) {
        const int gr = m0 + wm + mi * 16 + fq * 4 + r;
        float v = acc[mi][ni][r] + bv;
        if (EPI == 1) v = 0.5f * v * (1.f + erff(v * 0.70710678118f));
        if (EPI == 2) {
          v += resid[(size_t)gr * ldo + gc];
          ((float*)out)[(size_t)gr * ldo + gc] = v;
        } else {
          ((u16*)out)[(size_t)gr * ldo + gc] = f2bf(v);
        }
      }
    }
  }
}

// ---------------- MFMA flash attention ----------------------------------------
// Block = (b, h, c-half): 64 router rows vs all 4096 s. 4 waves over disjoint
// 32-s tiles, per-wave private LDS -> no barrier in main loop.
// Per tile: S^T[s,c] = mfma(k_tile, router) (K=16 zero-padded to 32);
// P = exp2(S^T) (max-free: scores are tiny); l-accum in-register;
// P truncation-packed to LDS rows [c][s]; ctx[c,d] += mfma(P, kT).
__global__ __launch_bounds__(256) void attn_mfma(const u16* __restrict__ kbf,
                                                 const float* __restrict__ router,
                                                 float* __restrict__ ctxb) {
  const int blk = blockIdx.x;
  const int bh = blk >> 1, chalf = blk & 1;
  const int b = bh >> 4, h = bh & 15;
  const int tid = threadIdx.x, w = tid >> 6, lane = tid & 63;
  const int l15 = lane & 15, lg = lane >> 4;

  __shared__ __align__(16) u16 Pl[4][64 * 40];   // per-wave P[c][s0..31] pad40
  __shared__ __align__(16) u16 kTl[4][16 * 40];  // per-wave k^T[d][s0..31] pad40
  __shared__ float ctxp[4][64][16];
  __shared__ float lp[4][64];

  // router B-frags (N=c, K=d zero-padded 16->32), scale folded (0.25*log2e)
  uint4 rB[4];
  {
    const float* rb = router + ((size_t)h * DC + chalf * 64) * 16;
#pragma unroll
    for (int nf = 0; nf < 4; nf++) {
      if (lg < 2) {
        const float* p = rb + (nf * 16 + l15) * 16 + lg * 8;
        float4 lo = *(const float4*)p;
        float4 hi = *(const float4*)(p + 4);
        lo.x *= ATT_SCALE; lo.y *= ATT_SCALE; lo.z *= ATT_SCALE; lo.w *= ATT_SCALE;
        hi.x *= ATT_SCALE; hi.y *= ATT_SCALE; hi.z *= ATT_SCALE; hi.w *= ATT_SCALE;
        rB[nf] = pack8(lo, hi);
      } else {
        rB[nf] = make_uint4(0, 0, 0, 0);
      }
    }
  }

  const u16* kg = kbf + (size_t)b * S_TOT * (NH * DKH) + h * 16;  // row stride 256

  f32x4 ctx[4];
#pragma unroll
  for (int i = 0; i < 4; i++) ctx[i] = (f32x4){0.f, 0.f, 0.f, 0.f};
  float ladd[4] = {0.f, 0.f, 0.f, 0.f};

  for (int tt = w; tt < 128; tt += 4) {
    const int s0 = tt * 32;
    // A-frags of k_tile: m = s, k = d (lg>=2 zero)
    uint4 kA[2];
#pragma unroll
    for (int mf = 0; mf < 2; mf++)
      kA[mf] = (lg < 2)
                   ? *(const uint4*)(kg + (size_t)(s0 + mf * 16 + l15) * 256 + lg * 8)
                   : make_uint4(0, 0, 0, 0);
    // stage k^T[d][s] for the PV B-operand
    {
      const int sl = lane & 31, dh = lane >> 5;
      uint4 kv = *(const uint4*)(kg + (size_t)(s0 + sl) * 256 + dh * 8);
      const u16* pv = (const u16*)&kv;
#pragma unroll
      for (int jj = 0; jj < 8; jj++) kTl[w][(dh * 8 + jj) * 40 + sl] = pv[jj];
    }
    // S^T = k_tile @ router^T
    f32x4 sc[2][4];
#pragma unroll
    for (int mf = 0; mf < 2; mf++)
#pragma unroll
      for (int nf = 0; nf < 4; nf++)
        sc[mf][nf] = __builtin_amdgcn_mfma_f32_16x16x32_bf16(
            __builtin_bit_cast(b16x8, kA[mf]), __builtin_bit_cast(b16x8, rB[nf]),
            (f32x4){0.f, 0.f, 0.f, 0.f}, 0, 0, 0);
    // exp2 + l-accum + truncation-pack P -> LDS rows [c][s]
#pragma unroll
    for (int mf = 0; mf < 2; mf++)
#pragma unroll
      for (int nf = 0; nf < 4; nf++) {
        float p0 = exp2f(sc[mf][nf][0]);
        float p1 = exp2f(sc[mf][nf][1]);
        float p2 = exp2f(sc[mf][nf][2]);
        float p3 = exp2f(sc[mf][nf][3]);
        ladd[nf] += (p0 + p1) + (p2 + p3);
        uint2 pk;
        pk.x = (__float_as_uint(p0) >> 16) | (__float_as_uint(p1) & 0xffff0000u);
        pk.y = (__float_as_uint(p2) >> 16) | (__float_as_uint(p3) & 0xffff0000u);
        *(uint2*)&Pl[w][(nf * 16 + l15) * 40 + mf * 16 + lg * 4] = pk;
      }
    // PV: ctx[c][d] += P[c][s] * kT[d][s]
    uint4 kB = *(const uint4*)&kTl[w][l15 * 40 + lg * 8];
#pragma unroll
    for (int mfc = 0; mfc < 4; mfc++) {
      uint4 pA = *(const uint4*)&Pl[w][(mfc * 16 + l15) * 40 + lg * 8];
      ctx[mfc] = __builtin_amdgcn_mfma_f32_16x16x32_bf16(
          __builtin_bit_cast(b16x8, pA), __builtin_bit_cast(b16x8, kB), ctx[mfc],
          0, 0, 0);
    }
  }

  // reduce l over the 4 row-groups (s-ownership) within the wave
#pragma unroll
  for (int nf = 0; nf < 4; nf++) {
    float v = ladd[nf];
    v += __shfl_xor(v, 16);
    v += __shfl_xor(v, 32);
    ladd[nf] = v;
  }
  if (lane < 16) {
#pragma unroll
    for (int nf = 0; nf < 4; nf++) lp[w][nf * 16 + lane] = ladd[nf];
  }
  // ctx C-layout: col = d = l15, row(c within frag) = lg*4 + r
#pragma unroll
  for (int mfc = 0; mfc < 4; mfc++)
#pragma unroll
    for (int r = 0; r < 4; r++) ctxp[w][mfc * 16 + lg * 4 + r][l15] = ctx[mfc][r];
  __syncthreads();
  // combine 4 waves, divide by softmax denom
#pragma unroll
  for (int i = 0; i < 4; i++) {
    const int idx = tid + i * 256;
    const int c = idx >> 4, d = idx & 15;
    const float L = lp[0][c] + lp[1][c] + lp[2][c] + lp[3][c];
    const float V = ctxp[0][c][d] + ctxp[1][c][d] + ctxp[2][c][d] + ctxp[3][c][d];
    ctxb[((size_t)b * DC + chalf * 64 + c) * (NH * DKH) + h * 16 + d] = V / L;
  }
}

// ---------------- ar[b,c,:] = ctx[b,c,:] @ out_w^T + out_b + pos_embd[c,:] -----
__global__ __launch_bounds__(256) void ar_kernel(const float* __restrict__ ctxb,
                                                 const float* __restrict__ owT,
                                                 const float* __restrict__ ob,
                                                 const float* __restrict__ pos,
                                                 float* __restrict__ ar) {
  const int b = blockIdx.x, g = blockIdx.y, n = threadIdx.x;
  __shared__ float cl[8][256];
#pragma unroll
  for (int j = 0; j < 8; j++)
    cl[j][n] = ctxb[((size_t)b * DC + g * 8 + j) * 256 + n];
  __syncthreads();
  float acc[8];
#pragma unroll
  for (int j = 0; j < 8; j++) acc[j] = ob[n] + pos[(size_t)(g * 8 + j) * 256 + n];
  for (int k = 0; k < 256; k++) {
    float wv = owT[(size_t)k * 256 + n];
#pragma unroll
    for (int j = 0; j < 8; j++) acc[j] += cl[j][k] * wv;
  }
#pragma unroll
  for (int j = 0; j < 8; j++) ar[((size_t)b * DC + g * 8 + j) * 256 + n] = acc[j];
}

// ---------------- t[b,q,:] = sum_c m_expand[q,c] * ar[b,c,:] -------------------
__global__ __launch_bounds__(256) void texp_kernel(const float* __restrict__ me,
                                                   const float* __restrict__ ar,
                                                   float* __restrict__ tb) {
  const int b = blockIdx.x, qg = blockIdx.y, d = threadIdx.x;
  __shared__ float ml[16][128];
  const int q0 = qg * 16;
  for (int i = threadIdx.x; i < 16 * 128; i += 256) {
    int qq = i >> 7, c = i & 127;
    ml[qq][c] = me[(size_t)(q0 + qq) * 128 + c];
  }
  __syncthreads();
  float acc[16];
#pragma unroll
  for (int qq = 0; qq < 16; qq++) acc[qq] = 0.f;
  for (int c = 0; c < 128; c++) {
    float v = ar[((size_t)b * DC + c) * 256 + d];
#pragma unroll
    for (int qq = 0; qq < 16; qq++) acc[qq] += ml[qq][c] * v;
  }
#pragma unroll
  for (int qq = 0; qq < 16; qq++)
    tb[((size_t)(b * QL + q0 + qq)) * 256 + d] = acc[qq];
}

// ---------------- LN1: y = LN(src + scale_tf[x]*t) ; write f32 y to d_out ------
__global__ __launch_bounds__(256) void ln1_kernel(
    const float* __restrict__ src, const float* __restrict__ tbuf,
    const float* __restrict__ stf, const float* __restrict__ g,
    const float* __restrict__ bb, float* __restrict__ yout) {
  const int w = threadIdx.x >> 6, lane = threadIdx.x & 63;
  const int r = blockIdx.x * 4 + w;
  const int b = r >> 12, x = (r >> 9) & 7, q = r & 511;
  const size_t base = (size_t)r * DM + lane * 4;
  float4 s4 = *(const float4*)(src + base);
  float4 t4 = *(const float4*)(tbuf + ((size_t)(b * QL + q) * DM + lane * 4));
  const float sc = stf[x];
  float v0 = s4.x + sc * t4.x, v1 = s4.y + sc * t4.y;
  float v2 = s4.z + sc * t4.z, v3 = s4.w + sc * t4.w;
  float sum = v0 + v1 + v2 + v3;
  float sq = v0 * v0 + v1 * v1 + v2 * v2 + v3 * v3;
#pragma unroll
  for (int off = 32; off; off >>= 1) {
    sum += __shfl_xor(sum, off);
    sq += __shfl_xor(sq, off);
  }
  const float mean = sum * (1.f / DM);
  const float var = sq * (1.f / DM) - mean * mean;
  const float rs = rsqrtf(var + 1e-5f);
  float4 gv = *(const float4*)(g + lane * 4);
  float4 bv = *(const float4*)(bb + lane * 4);
  float4 o;
  o.x = (v0 - mean) * rs * gv.x + bv.x;
  o.y = (v1 - mean) * rs * gv.y + bv.y;
  o.z = (v2 - mean) * rs * gv.z + bv.z;
  o.w = (v3 - mean) * rs * gv.w + bv.w;
  *(float4*)(yout + base) = o;
}

// ---------------- LN2: in-place on d_out --------------------------------------
__global__ __launch_bounds__(256) void ln2_kernel(float* __restrict__ io,
                                                  const float* __restrict__ g,
                                                  const float* __restrict__ bb) {
  const int w = threadIdx.x >> 6, lane = threadIdx.x & 63;
  const int r = blockIdx.x * 4 + w;
  const size_t base = (size_t)r * DM + lane * 4;
  float4 v4 = *(const float4*)(io + base);
  float sum = v4.x + v4.y + v4.z + v4.w;
  float sq = v4.x * v4.x + v4.y * v4.y + v4.z * v4.z + v4.w * v4.w;
#pragma unroll
  for (int off = 32; off; off >>= 1) {
    sum += __shfl_xor(sum, off);
    sq += __shfl_xor(sq, off);
  }
  const float mean = sum * (1.f / DM);
  const float var = sq * (1.f / DM) - mean * mean;
  const float rs = rsqrtf(var + 1e-5f);
  float4 gv = *(const float4*)(g + lane * 4);
  float4 bv = *(const float4*)(bb + lane * 4);
  float4 o;
  o.x = (v4.x - mean) * rs * gv.x + bv.x;
  o.y = (v4.y - mean) * rs * gv.y + bv.y;
  o.z = (v4.z - mean) * rs * gv.z + bv.z;
  o.w = (v4.w - mean) * rs * gv.w + bv.w;
  *(float4*)(io + base) = o;
}

extern "C" void kernel_launch(void* const* d_in, const int* in_sizes, int n_in,
                              void* d_out, int out_size, void* d_ws, size_t ws_size,
                              hipStream_t stream) {
  const float* src = (const float*)d_in[0];
  const float* router = (const float*)d_in[1];
  const float* wk_w = (const float*)d_in[2];
  const float* wk_b = (const float*)d_in[3];
  const float* out_w = (const float*)d_in[4];
  const float* out_b = (const float*)d_in[5];
  const float* m_exp = (const float*)d_in[6];
  const float* pos = (const float*)d_in[7];
  const float* stf = (const float*)d_in[8];
  const float* ln1g = (const float*)d_in[9];
  const float* ln1b = (const float*)d_in[10];
  const float* f1w = (const float*)d_in[11];
  const float* f1b = (const float*)d_in[12];
  const float* f2w = (const float*)d_in[13];
  const float* f2b = (const float*)d_in[14];
  const float* ln2g = (const float*)d_in[15];
  const float* ln2b = (const float*)d_in[16];
  float* out = (float*)d_out;

  unsigned char* ws = (unsigned char*)d_ws;
  u16* k_bf = (u16*)(ws + 0);               // 33,554,432 B
  u16* h_bf = (u16*)(ws + 33554432);        // 134,217,728 B
  u16* wkw_bf = (u16*)(ws + 167772160);     // 131,072 B
  u16* f1w_bf = (u16*)(ws + 167903232);     // 524,288 B
  u16* f2w_bf = (u16*)(ws + 168427520);     // 524,288 B
  float* owT = (float*)(ws + 168951808);    // 262,144 B
  float* ctxb = (float*)(ws + 169213952);   // 2,097,152 B
  float* arb = (float*)(ws + 171311104);    // 2,097,152 B
  float* tb = (float*)(ws + 173408256);     // 8,388,608 B  (total 181,796,864 B)

  cvt_kernel<<<64, 256, 0, stream>>>(wk_w, wkw_bf, 256 * 256 / 4);
  cvt_kernel<<<256, 256, 0, stream>>>(f1w, f1w_bf, DFF * DM / 4);
  cvt_kernel<<<256, 256, 0, stream>>>(f2w, f2w_bf, DM * DFF / 4);
  transp_kernel<<<256, 256, 0, stream>>>(out_w, owT);

  // K-projection: k = src @ Wk_w^T + Wk_b  (f32 A staged->bf16; bf16 out [b*S][h*16+d])
  gemm_bf16<0, 1, 2><<<1024, 256, 0, stream>>>(src, wkw_bf, wk_b, nullptr,
                                               k_bf, DM, DM);
  attn_mfma<<<512, 256, 0, stream>>>(k_bf, router, ctxb);
  ar_kernel<<<dim3(16, 16), 256, 0, stream>>>(ctxb, owT, out_b, pos, arb);
  texp_kernel<<<dim3(16, 32), 256, 0, stream>>>(m_exp, arb, tb);
  ln1_kernel<<<16384, 256, 0, stream>>>(src, tb, stf, ln1g, ln1b, out);

  // FFN1: h = gelu(y @ ff1_w^T + b1)  (f32 A = d_out, bf16 h in ws)
  gemm_bf16<1, 1, 8><<<4096, 256, 0, stream>>>(out, f1w_bf, f1b, nullptr,
                                               h_bf, DM, DFF);
  // FFN2: pre-LN2 = y + h @ ff2_w^T + b2  (f32, in-place on d_out)
  gemm_bf16<2, 0, 2><<<1024, 256, 0, stream>>>(h_bf, f2w_bf, f2b, out,
                                               out, DFF, DM);
  ln2_kernel<<<16384, 256, 0, stream>>>(out, ln2g, ln2b);
}